// Round 13
// baseline (8830.433 us; speedup 1.0000x reference)
//
#include <hip/hip_runtime.h>
#include <math.h>

#define NA    360
#define ZPT   8
#define PITCH 65            // float2 cells per row stride (flat /65 map, 65 cols)
#define NCELL 2048          // staged cells: 8 per thread x 256 threads
#define VLO_MAX 224         // staged rows vlo..vlo+31 <= 255
#define ULO_MAX 191         // staged cols ulo..ulo+64 <= 255

// Cone-beam backprojection, batch-fused: both batches' patches staged as
// interleaved float2 cells {b0,b1}. The 4 bilinear taps for BOTH batches are
// 2x ds_read2_b64 per k -> LDS instruction count per voxel-angle halves
// (R12 diagnosis: LDS-pipe saturated; bytes/va fixed at 16B, instrs are the
// lever). Geometry (shared by both batches): dz=dy=dx=2mm, dv=du=2mm,
// DSO=1000, DSD=1536, mag in [1.302,1.872]; iv in (8.6,246.4) -> v never
// clamps, v0+1 in-bounds. 24-row v-window + 52-col u-window coverage proven
// exhaustively R5-R12 (absmax 0.25 stable). Staging: registers (16 dwords in
// flight, T14 split: issue -> compute -> write -> 1 barrier/angle);
// global_load_lds can't interleave (fixed lane*4 dest).

typedef float v2f __attribute__((ext_vector_type(2)));

struct __align__(16) Ang { float c, s; int ulo, vlo; };

__device__ __forceinline__ Ang ang_setup(int i, float xclo, float xchi,
                                         float yclo, float ychi,
                                         float zvlo, float zvhi)
{
    float th = (float)i * (float)(2.0 * M_PI / (double)NA);
    float s, c; sincosf(th, &s, &c);
    const float a0 = xclo*c, a1 = xchi*c, b0 = yclo*s, b1 = ychi*s;
    const float xr0 = a0+b0, xr1 = a0+b1, xr2 = a1+b0, xr3 = a1+b1;
    const float xmn = fminf(fminf(xr0,xr1), fminf(xr2,xr3));
    const float xmx = fmaxf(fmaxf(xr0,xr1), fmaxf(xr2,xr3));
    const float c0 = yclo*c, c1 = ychi*c, d0 = xclo*s, d1 = xchi*s;
    const float yr0 = c0-d0, yr1 = c0-d1, yr2 = c1-d0, yr3 = c1-d1;
    const float ymn = fminf(fminf(yr0,yr1), fminf(yr2,yr3));
    const float ymx = fmaxf(fmaxf(yr0,yr1), fmaxf(yr2,yr3));
    const float mlo = 1536.f * __builtin_amdgcn_rcpf(1000.f - xmn);
    const float mhi = 1536.f * __builtin_amdgcn_rcpf(1000.f - xmx);
    const float umn = fminf(fminf(ymn*mlo, ymn*mhi), fminf(ymx*mlo, ymx*mhi));
    int u_lo = (int)floorf(fmaf(umn, 0.5f, 127.5f)) - 1;
    u_lo = u_lo < 0 ? 0 : (u_lo > ULO_MAX ? ULO_MAX : u_lo);
    const float vmn = fminf(fminf(zvlo*mlo, zvlo*mhi), fminf(zvhi*mlo, zvhi*mhi));
    int v_lo = (int)floorf(vmn + 127.5f) - 1;
    v_lo = v_lo < 0 ? 0 : (v_lo > VLO_MAX ? VLO_MAX : v_lo);
    Ang g; g.c = c; g.s = s; g.ulo = u_lo; g.vlo = v_lo;
    return g;
}

// Issue this thread's 16 staging loads (8 cells x 2 batches) for one angle.
__device__ __forceinline__ void stage_issue(const char* pa0, const char* pa1,
                                            const int goffB[8],
                                            float t0[8], float t1[8])
{
    #pragma unroll
    for (int i = 0; i < 8; ++i) {
        t0[i] = *(const float*)(pa0 + goffB[i]);
        t1[i] = *(const float*)(pa1 + goffB[i]);
    }
}

// Write staged values as interleaved float2 cells. dst = &patch[buf][wv*512+lane].
__device__ __forceinline__ void stage_write(v2f* dst,
                                            const float t0[8], const float t1[8])
{
    #pragma unroll
    for (int i = 0; i < 8; ++i)
        dst[i * 64] = (v2f){t0[i], t1[i]};
}

__device__ __forceinline__ void compute_angle2(const v2f* __restrict__ smb,
    const Ang g, float xc, float yc, float zf0, v2f acc[ZPT])
{
    const float xr  = xc*g.c + yc*g.s;
    const float yr  = yc*g.c - xc*g.s;
    const float mag = 1536.f * __builtin_amdgcn_rcpf(1000.f - xr);
    const float iu  = fmaf(yr*mag, 0.5f, 127.5f);
    const bool uval = (iu >= 0.f) && (iu <= 255.f);
    const float iuc = fminf(fmaxf(iu, 0.f), 255.f);
    int u0 = (int)iuc; u0 = u0 > 254 ? 254 : u0;
    const float fu  = iuc - (float)u0;
    const float w   = uval ? 1.f : 0.f;
    const float wu1 = fu*w, wu0 = w - wu1;
    const v2f   w0v = {wu0, wu0};
    const v2f   w1v = {wu1, wu1};
    const int   ui  = u0 - g.ulo;                        // 0..63
    const float ivb = fmaf(zf0, mag, 127.5f) - (float)g.vlo;
    #pragma unroll
    for (int k = 0; k < ZPT; ++k) {
        const float ivl = fmaf((float)k, mag, ivb);
        const int   v0  = (int)ivl;                      // >0 -> trunc==floor
        const float fv  = __builtin_amdgcn_fractf(ivl);
        const v2f* cell = smb + (v0 * PITCH + ui);
        const v2f a00 = cell[0];                         // {b0,b1} at (v0,  u0)
        const v2f a01 = cell[1];                         // (v0,  u0+1)
        const v2f a10 = cell[PITCH];                     // (v0+1,u0)
        const v2f a11 = cell[PITCH+1];                   // (v0+1,u0+1)
        const v2f fvv = {fv, fv};
        const v2f r0 = __builtin_elementwise_fma(fvv, a10 - a00, a00);
        const v2f r1 = __builtin_elementwise_fma(fvv, a11 - a01, a01);
        acc[k] = __builtin_elementwise_fma(w0v, r0, acc[k]);
        acc[k] = __builtin_elementwise_fma(w1v, r1, acc[k]);
    }
}

__global__ __launch_bounds__(256, 4) void bp_kernel(const float* __restrict__ proj,
                                                    float* __restrict__ out) {
    __shared__ Ang ang_sh[NA];
    __shared__ v2f patch[2][NCELL];      // 2 x 16KB, interleaved {b0,b1}

    const int tid = threadIdx.y * 16 + threadIdx.x;

    const int zg = blockIdx.x;            // z-group (16)
    const int t  = blockIdx.y;            // xy tile (64)
    const int x0 = (t & 7) * 16;
    const int y0 = (t >> 3) * 16;
    const int zb = zg * ZPT;

    const float zf0  = (float)zb - 63.5f;
    const float xclo = ((float)x0 - 63.5f) * 2.f, xchi = xclo + 30.f;
    const float yclo = ((float)y0 - 63.5f) * 2.f, ychi = yclo + 30.f;

    for (int i = tid; i < NA; i += 256)
        ang_sh[i] = ang_setup(i, xclo, xchi, yclo, ychi, zf0, zf0 + 7.f);
    __syncthreads();

    // per-lane staging source offsets (constant across angles):
    // cell flat f = wv*512 + i*64 + lane -> detector (r,c) = (f/65, f%65)
    const int wv   = tid >> 6;
    const int lane = tid & 63;
    int goffB[8];
    #pragma unroll
    for (int i = 0; i < 8; ++i) {
        const int flat = wv * 512 + i * 64 + lane;
        const int r  = flat / PITCH;          // init-only exact division
        const int cc = flat - r * PITCH;
        goffB[i] = (r * 256 + cc) * 4;        // detector-row-major, bytes
    }

    const char* pb0 = (const char*)proj;                    // batch 0 slab
    const char* pb1 = pb0 + (size_t)NA * 65536 * 4;         // batch 1 slab

    const float xc = ((float)(x0 + threadIdx.x) - 63.5f) * 2.f;
    const float yc = ((float)(y0 + threadIdx.y) - 63.5f) * 2.f;

    v2f* w0 = &patch[0][wv * 512 + lane];   // this thread's write slots
    v2f* w1 = &patch[1][wv * 512 + lane];

    v2f acc[ZPT];
    #pragma unroll
    for (int k = 0; k < ZPT; ++k) acc[k] = (v2f){0.f, 0.f};

    float t0[8], t1[8];

    // prologue: stage angle 0 into patch[0]
    {
        const Ang g = ang_sh[0];
        const uint32_t aoff = __builtin_amdgcn_readfirstlane(
            ((uint32_t)g.vlo << 10) + ((uint32_t)g.ulo << 2));
        stage_issue(pb0 + aoff, pb1 + aoff, goffB, t0, t1);
        stage_write(w0, t0, t1);
    }
    __syncthreads();

    for (int a = 0; a < NA; a += 2) {
        {   // issue a+1 loads early; write late (hidden under compute of a)
            const Ang g = ang_sh[a + 1];
            const uint32_t aoff = __builtin_amdgcn_readfirstlane(
                (uint32_t)(a + 1) * 262144u +
                ((uint32_t)g.vlo << 10) + ((uint32_t)g.ulo << 2));
            stage_issue(pb0 + aoff, pb1 + aoff, goffB, t0, t1);
        }
        compute_angle2(patch[0], ang_sh[a], xc, yc, zf0, acc);
        stage_write(w1, t0, t1);
        __syncthreads();

        if (a + 2 < NA) {
            const Ang g = ang_sh[a + 2];
            const uint32_t aoff = __builtin_amdgcn_readfirstlane(
                (uint32_t)(a + 2) * 262144u +
                ((uint32_t)g.vlo << 10) + ((uint32_t)g.ulo << 2));
            stage_issue(pb0 + aoff, pb1 + aoff, goffB, t0, t1);
        }
        compute_angle2(patch[1], ang_sh[a + 1], xc, yc, zf0, acc);
        if (a + 2 < NA) stage_write(w0, t0, t1);
        __syncthreads();
    }

    float* o0 = out + (((size_t)zb) * 128 + (y0 + threadIdx.y)) * 128
                    + (x0 + threadIdx.x);
    float* o1 = o0 + (size_t)128 * 128 * 128;   // batch 1 volume
    #pragma unroll
    for (int k = 0; k < ZPT; ++k) {
        o0[(size_t)k * (128 * 128)] = acc[k].x;
        o1[(size_t)k * (128 * 128)] = acc[k].y;
    }
}

extern "C" void kernel_launch(void* const* d_in, const int* in_sizes, int n_in,
                              void* d_out, int out_size, void* d_ws, size_t ws_size,
                              hipStream_t stream) {
    const float* proj = (const float*)d_in[0];
    float* out = (float*)d_out;
    dim3 grid(128 / ZPT, 64, 1);   // (z-groups, xy-tiles) = 1024 blocks, batch fused
    dim3 block(16, 16, 1);
    hipLaunchKernelGGL(bp_kernel, grid, block, 0, stream, proj, out);
}

// Round 14
// 785.813 us; speedup vs baseline: 11.2373x; 11.2373x over previous
//
#include <hip/hip_runtime.h>
#include <math.h>

#define NA    360
#define ZPT   8
#define NSTG  4096          // floats per buffer: [32 rows][128] = 16 KB
#define VLO_MAX 224         // staged rows vlo..vlo+31 <= 255
#define ULO_MAX 192         // staged cols ulo..ulo+63 <= 255
#define BSTRIDE 94371840    // bytes per batch slab = 360*65536*4

// Cone-beam backprojection, batch-fused, LDS-staged via global_load_lds ONLY
// (R13 lesson: register-staged scattered loads -> FETCH 16GB, 9ms; gl_lds
// keeps FETCH ~0.6GB). Patch layout [32 v-rows][128]: row = [batch0 cols
// 0..63 | batch1 cols 0..63]; both batches' 8 bilinear taps come from ONE
// vaddr (v0<<7)+ui via 4x ds_read2_b32 imm offsets {0,1},{64,65},{128,129},
// {192,193}. Geometry shared by both batches -> per-angle setup and per-k
// index math serve two outputs (VALU/va ~10 -> ~6.7); barriers/output halve.
// Geometry: dz=dy=dx=2mm, dv=du=2mm, DSO=1000, DSD=1536, mag in [1.302,1.872];
// iv in (8.6,246.4) -> v never clamps, v0+1 in-bounds. 24-row v-window and
// 52-col u-window coverage proven exhaustively R5-R12 (absmax 0.25 stable).

typedef float v2f __attribute__((ext_vector_type(2)));
typedef __attribute__((address_space(1))) const void gas_t;
typedef __attribute__((address_space(3))) void las_t;

__device__ __forceinline__ int2 bbox_angle(float c, float s,
    float xclo, float xchi, float yclo, float ychi, float zvlo, float zvhi)
{
    const float a0 = xclo*c, a1 = xchi*c, b0 = yclo*s, b1 = ychi*s;
    const float xr0 = a0+b0, xr1 = a0+b1, xr2 = a1+b0, xr3 = a1+b1;
    const float xmn = fminf(fminf(xr0,xr1), fminf(xr2,xr3));
    const float xmx = fmaxf(fmaxf(xr0,xr1), fmaxf(xr2,xr3));
    const float c0 = yclo*c, c1 = ychi*c, d0 = xclo*s, d1 = xchi*s;
    const float yr0 = c0-d0, yr1 = c0-d1, yr2 = c1-d0, yr3 = c1-d1;
    const float ymn = fminf(fminf(yr0,yr1), fminf(yr2,yr3));
    const float ymx = fmaxf(fmaxf(yr0,yr1), fmaxf(yr2,yr3));
    const float mlo = 1536.f * __builtin_amdgcn_rcpf(1000.f - xmn);
    const float mhi = 1536.f * __builtin_amdgcn_rcpf(1000.f - xmx);
    const float umn = fminf(fminf(ymn*mlo, ymn*mhi), fminf(ymx*mlo, ymx*mhi));
    int u_lo = (int)floorf(fmaf(umn, 0.5f, 127.5f)) - 1;
    u_lo = u_lo < 0 ? 0 : (u_lo > ULO_MAX ? ULO_MAX : u_lo);
    const float vmn = fminf(fminf(zvlo*mlo, zvlo*mhi), fminf(zvhi*mlo, zvhi*mhi));
    int v_lo = (int)floorf(vmn + 127.5f) - 1;
    v_lo = v_lo < 0 ? 0 : (v_lo > VLO_MAX ? VLO_MAX : v_lo);
    return make_int2(u_lo, v_lo);
}

// Wave w stages LDS floats [w*1024 .. w*1024+1023] (rows 8w..8w+7, both
// batches) with 4 width-16 global_load_lds; per-lane source offset goffB[i]
// is constant across angles (includes batch-slab selector).
__device__ __forceinline__ void stage4(const char* gb, float* ldsw,
                                       const int goffB[4]) {
    #pragma unroll
    for (int i = 0; i < 4; ++i) {
        __builtin_amdgcn_global_load_lds(
            (gas_t*)(gb + goffB[i]),
            (las_t*)(ldsw + i * 256), 16, 0, 0);
    }
}

__device__ __forceinline__ void compute_angle(const float* __restrict__ smb,
    float c, float s, float xc, float yc, float zf0, int u_lo, int v_lo,
    v2f accA[ZPT], v2f accB[ZPT])
{
    const float xr  = xc*c + yc*s;
    const float yr  = yc*c - xc*s;
    const float mag = 1536.f * __builtin_amdgcn_rcpf(1000.f - xr);
    const float iu  = fmaf(yr*mag, 0.5f, 127.5f);
    const bool uval = (iu >= 0.f) && (iu <= 255.f);
    const float iuc = fminf(fmaxf(iu, 0.f), 255.f);
    int u0 = (int)iuc; u0 = u0 > 254 ? 254 : u0;
    const float fu  = iuc - (float)u0;
    const float w   = uval ? 1.f : 0.f;
    const float wu1 = fu*w, wu0 = w - wu1;
    const v2f   wuv = {wu0, wu1};
    const int   ui  = u0 - u_lo;                         // 0..63
    const float ivb = fmaf(zf0, mag, 127.5f) - (float)v_lo;
    #pragma unroll
    for (int k = 0; k < ZPT; ++k) {
        const float ivl = fmaf((float)k, mag, ivb);
        const int   v0  = (int)ivl;                      // >0 -> trunc==floor
        const float fv  = __builtin_amdgcn_fractf(ivl);
        const float* r  = smb + ((v0 << 7) + ui);
        const v2f a0 = {r[0],   r[1]};                   // batch0 row v0
        const v2f b0 = {r[64],  r[65]};                  // batch1 row v0
        const v2f a1 = {r[128], r[129]};                 // batch0 row v0+1
        const v2f b1 = {r[192], r[193]};                 // batch1 row v0+1
        const v2f fvv = {fv, fv};
        const v2f qa = __builtin_elementwise_fma(fvv, a1 - a0, a0);
        const v2f qb = __builtin_elementwise_fma(fvv, b1 - b0, b0);
        accA[k] = __builtin_elementwise_fma(wuv, qa, accA[k]);
        accB[k] = __builtin_elementwise_fma(wuv, qb, accB[k]);
    }
}

__global__ __launch_bounds__(256, 4) void bp_kernel(const float* __restrict__ proj,
                                                    float* __restrict__ out) {
    __shared__ float2 cs_sh[NA];
    __shared__ int2   bb_sh[NA];
    __shared__ float  patch[2][NSTG];

    const int tid = threadIdx.y * 16 + threadIdx.x;

    const int zg = blockIdx.x;            // z-group (16)
    const int t  = blockIdx.y;            // xy tile (64)
    const int x0 = (t & 7) * 16;
    const int y0 = (t >> 3) * 16;
    const int zb = zg * ZPT;

    const float zf0  = (float)zb - 63.5f;
    const float xclo = ((float)x0 - 63.5f) * 2.f, xchi = xclo + 30.f;
    const float yclo = ((float)y0 - 63.5f) * 2.f, ychi = yclo + 30.f;

    for (int i = tid; i < NA; i += 256) {
        float th = (float)i * (float)(2.0 * M_PI / (double)NA);
        float sv, cv; sincosf(th, &sv, &cv);
        cs_sh[i] = make_float2(cv, sv);
        bb_sh[i] = bbox_angle(cv, sv, xclo, xchi, yclo, ychi, zf0, zf0 + 7.f);
    }
    __syncthreads();

    // per-lane staging source offsets (constant across angles):
    // LDS float f = wv*1024 + i*256 + lane*4 -> row v=f>>7, batch=(f>>6)&1,
    // col=f&63. Source = angle-window origin + batch*BSTRIDE + v*1024 + col*4.
    const int wv   = tid >> 6;
    const int lane = tid & 63;
    int goffB[4];
    #pragma unroll
    for (int i = 0; i < 4; ++i) {
        const int f    = wv * 1024 + i * 256 + lane * 4;
        const int v    = f >> 7;
        const int bsel = (f >> 6) & 1;
        const int col  = f & 63;
        goffB[i] = bsel * BSTRIDE + v * 1024 + col * 4;
    }

    const char* projB = (const char*)proj;
    const float xc = ((float)(x0 + threadIdx.x) - 63.5f) * 2.f;
    const float yc = ((float)(y0 + threadIdx.y) - 63.5f) * 2.f;

    float* l0 = &patch[0][wv * 1024];
    float* l1 = &patch[1][wv * 1024];

    v2f accA[ZPT], accB[ZPT];
    #pragma unroll
    for (int k = 0; k < ZPT; ++k) {
        accA[k] = (v2f){0.f, 0.f};
        accB[k] = (v2f){0.f, 0.f};
    }

    // prologue: stage angle 0 into patch[0]
    {
        const int2 lo = bb_sh[0];
        const uint32_t aoff = __builtin_amdgcn_readfirstlane(
            ((uint32_t)lo.y << 10) + ((uint32_t)lo.x << 2));
        stage4(projB + aoff, l0, goffB);
    }
    __syncthreads();   // implicit vmcnt(0) drain -> patch[0] ready

    for (int a = 0; a < NA; a += 2) {
        {   // stage a+1 -> patch[1] while computing a from patch[0]
            const int2 lo = bb_sh[a + 1];
            const uint32_t aoff = __builtin_amdgcn_readfirstlane(
                (uint32_t)(a + 1) * 262144u +
                ((uint32_t)lo.y << 10) + ((uint32_t)lo.x << 2));
            stage4(projB + aoff, l1, goffB);
        }
        {
            const float2 cs = cs_sh[a];
            const int2   lo = bb_sh[a];
            compute_angle(patch[0], cs.x, cs.y, xc, yc, zf0, lo.x, lo.y,
                          accA, accB);
        }
        __syncthreads();
        if (a + 2 < NA) {   // stage a+2 -> patch[0] while computing a+1
            const int2 lo = bb_sh[a + 2];
            const uint32_t aoff = __builtin_amdgcn_readfirstlane(
                (uint32_t)(a + 2) * 262144u +
                ((uint32_t)lo.y << 10) + ((uint32_t)lo.x << 2));
            stage4(projB + aoff, l0, goffB);
        }
        {
            const float2 cs = cs_sh[a + 1];
            const int2   lo = bb_sh[a + 1];
            compute_angle(patch[1], cs.x, cs.y, xc, yc, zf0, lo.x, lo.y,
                          accA, accB);
        }
        __syncthreads();
    }

    float* o0 = out + (((size_t)zb) * 128 + (y0 + threadIdx.y)) * 128
                    + (x0 + threadIdx.x);
    float* o1 = o0 + (size_t)128 * 128 * 128;   // batch 1 volume
    #pragma unroll
    for (int k = 0; k < ZPT; ++k) {
        o0[(size_t)k * (128 * 128)] = accA[k].x + accA[k].y;
        o1[(size_t)k * (128 * 128)] = accB[k].x + accB[k].y;
    }
}

extern "C" void kernel_launch(void* const* d_in, const int* in_sizes, int n_in,
                              void* d_out, int out_size, void* d_ws, size_t ws_size,
                              hipStream_t stream) {
    const float* proj = (const float*)d_in[0];
    float* out = (float*)d_out;
    dim3 grid(128 / ZPT, 64, 1);   // (z-groups, xy-tiles) = 1024 blocks, batch fused
    dim3 block(16, 16, 1);
    hipLaunchKernelGGL(bp_kernel, grid, block, 0, stream, proj, out);
}

// Round 16
// 769.753 us; speedup vs baseline: 11.4718x; 1.0209x over previous
//
#include <hip/hip_runtime.h>
#include <math.h>

#define NA    360
#define ZPT   8
#define CROWS 24            // staged v-rows (24-row window proven R5-R14)
#define CPITCH 64           // cells per row (u-window 52 proven; 64 staged)
#define NCELL (CROWS*CPITCH)   // 1536 cells = 12 KB per buffer
#define VLO_MAX 232         // staged rows vlo..vlo+23 <= 255
#define ULO_MAX 192         // ui <= 62 -> ui+1 tap <= 63 stays in-row (R15 bug: 191)
#define BSTRIDE 94371840    // bytes per batch slab = 360*65536*4

// Cone-beam backprojection, batch-fused with INTERLEAVED float2 cells.
// Cell (v,u) = {batch0[v,u], batch1[v,u]} (8B, always 8B-aligned). The 8
// bilinear taps (4 per batch) = cells (v0,ui),(v0+1,ui),(v0,ui+1),(v0+1,ui+1)
// = 2x ds_read2_b64 on one vaddr (offsets {0,64},{1,65}) -> halves LDS tap
// instructions vs 4x ds_read2_b32 (R14 diagnosis: LDS-pipe saturated at ~2x
// the bytes floor due to narrow accesses). Staging stays global_load_lds ONLY
// (R13 lesson: register-staged scatter -> FETCH 16GB). Width-4 staging,
// 12 instrs/wave; decode flat dword f -> batch=f&1, ucol=(f>>1)&63, v=f>>7.
// ULO_MAX=192 is LOAD-BEARING: ui = u0-u_lo <= 254-192 = 62, so the ui+1 tap
// never crosses the 64-col row (R15's 191 let ui=63 -> wrapped into the next
// v-row with full weight -> absmax 9.5).
// Geometry (shared by both batches): dz=dy=dx=2mm, dv=du=2mm, DSO=1000,
// DSD=1536, mag in [1.302,1.872]; iv in (8.6,246.4) -> v never clamps,
// v0+1 in-bounds; v0-vlo in [0,22] (24-row window proven R5). Weight-0
// clamped taps may read garbage cells (same as R8-R14; numerically inert).

typedef float v2f __attribute__((ext_vector_type(2)));
typedef __attribute__((address_space(1))) const void gas_t;
typedef __attribute__((address_space(3))) void las_t;

__device__ __forceinline__ int2 bbox_angle(float c, float s,
    float xclo, float xchi, float yclo, float ychi, float zvlo, float zvhi)
{
    const float a0 = xclo*c, a1 = xchi*c, b0 = yclo*s, b1 = ychi*s;
    const float xr0 = a0+b0, xr1 = a0+b1, xr2 = a1+b0, xr3 = a1+b1;
    const float xmn = fminf(fminf(xr0,xr1), fminf(xr2,xr3));
    const float xmx = fmaxf(fmaxf(xr0,xr1), fmaxf(xr2,xr3));
    const float c0 = yclo*c, c1 = ychi*c, d0 = xclo*s, d1 = xchi*s;
    const float yr0 = c0-d0, yr1 = c0-d1, yr2 = c1-d0, yr3 = c1-d1;
    const float ymn = fminf(fminf(yr0,yr1), fminf(yr2,yr3));
    const float ymx = fmaxf(fmaxf(yr0,yr1), fmaxf(yr2,yr3));
    const float mlo = 1536.f * __builtin_amdgcn_rcpf(1000.f - xmn);
    const float mhi = 1536.f * __builtin_amdgcn_rcpf(1000.f - xmx);
    const float umn = fminf(fminf(ymn*mlo, ymn*mhi), fminf(ymx*mlo, ymx*mhi));
    int u_lo = (int)floorf(fmaf(umn, 0.5f, 127.5f)) - 1;
    u_lo = u_lo < 0 ? 0 : (u_lo > ULO_MAX ? ULO_MAX : u_lo);
    const float vmn = fminf(fminf(zvlo*mlo, zvlo*mhi), fminf(zvhi*mlo, zvhi*mhi));
    int v_lo = (int)floorf(vmn + 127.5f) - 1;
    v_lo = v_lo < 0 ? 0 : (v_lo > VLO_MAX ? VLO_MAX : v_lo);
    return make_int2(u_lo, v_lo);
}

// Wave w stages buffer dwords [w*768 .. w*768+767] (12 width-4 gl_lds).
__device__ __forceinline__ void stage12(const char* gb, float* ldsw,
                                        const int goffB[12]) {
    #pragma unroll
    for (int i = 0; i < 12; ++i) {
        __builtin_amdgcn_global_load_lds(
            (gas_t*)(gb + goffB[i]),
            (las_t*)(ldsw + i * 64), 4, 0, 0);
    }
}

__device__ __forceinline__ void compute_angle(const v2f* __restrict__ smb,
    float c, float s, float xc, float yc, float zf0, int u_lo, int v_lo,
    v2f acc[ZPT])
{
    const float xr  = xc*c + yc*s;
    const float yr  = yc*c - xc*s;
    const float mag = 1536.f * __builtin_amdgcn_rcpf(1000.f - xr);
    const float iu  = fmaf(yr*mag, 0.5f, 127.5f);
    const bool uval = (iu >= 0.f) && (iu <= 255.f);
    const float iuc = fminf(fmaxf(iu, 0.f), 255.f);
    int u0 = (int)iuc; u0 = u0 > 254 ? 254 : u0;
    const float fu  = iuc - (float)u0;
    const float w   = uval ? 1.f : 0.f;
    const float wu1 = fu*w, wu0 = w - wu1;
    const v2f   w0v = {wu0, wu0};
    const v2f   w1v = {wu1, wu1};
    const int   ui  = u0 - u_lo;                         // <= 62 for valid taps
    const float ivb = fmaf(zf0, mag, 127.5f) - (float)v_lo;
    #pragma unroll
    for (int k = 0; k < ZPT; ++k) {
        const float ivl = fmaf((float)k, mag, ivb);
        const int   v0  = (int)ivl;                      // >0 -> trunc==floor
        const float fv  = __builtin_amdgcn_fractf(ivl);
        const v2f* cell = smb + ((v0 << 6) + ui);
        const v2f c00 = cell[0];                         // {b0,b1}@(v0,  u0)
        const v2f c10 = cell[CPITCH];                    // (v0+1,u0)   read2_b64
        const v2f c01 = cell[1];                         // (v0,  u0+1)
        const v2f c11 = cell[CPITCH+1];                  // (v0+1,u0+1) read2_b64
        const v2f fvv = {fv, fv};
        const v2f q0 = __builtin_elementwise_fma(fvv, c10 - c00, c00);
        const v2f q1 = __builtin_elementwise_fma(fvv, c11 - c01, c01);
        acc[k] = __builtin_elementwise_fma(w0v, q0, acc[k]);
        acc[k] = __builtin_elementwise_fma(w1v, q1, acc[k]);
    }
}

__global__ __launch_bounds__(256, 4) void bp_kernel(const float* __restrict__ proj,
                                                    float* __restrict__ out) {
    __shared__ float2 cs_sh[NA];
    __shared__ int2   bb_sh[NA];
    __shared__ v2f    patch[2][NCELL];   // interleaved {b0,b1} cells

    const int tid = threadIdx.y * 16 + threadIdx.x;

    const int zg = blockIdx.x;            // z-group (16)
    const int t  = blockIdx.y;            // xy tile (64)
    const int x0 = (t & 7) * 16;
    const int y0 = (t >> 3) * 16;
    const int zb = zg * ZPT;

    const float zf0  = (float)zb - 63.5f;
    const float xclo = ((float)x0 - 63.5f) * 2.f, xchi = xclo + 30.f;
    const float yclo = ((float)y0 - 63.5f) * 2.f, ychi = yclo + 30.f;

    for (int i = tid; i < NA; i += 256) {
        float th = (float)i * (float)(2.0 * M_PI / (double)NA);
        float sv, cv; sincosf(th, &sv, &cv);
        cs_sh[i] = make_float2(cv, sv);
        bb_sh[i] = bbox_angle(cv, sv, xclo, xchi, yclo, ychi, zf0, zf0 + 7.f);
    }
    __syncthreads();

    // per-lane staging source offsets (constant across angles):
    // buffer dword f = wv*768 + i*64 + lane -> batch=f&1, ucol=(f>>1)&63,
    // v=f>>7. Source = angle origin + batch*BSTRIDE + v*1024 + ucol*4.
    const int wv   = tid >> 6;
    const int lane = tid & 63;
    int goffB[12];
    #pragma unroll
    for (int i = 0; i < 12; ++i) {
        const int f    = wv * 768 + i * 64 + lane;
        const int bsel = f & 1;
        const int ucol = (f >> 1) & 63;
        const int v    = f >> 7;
        goffB[i] = bsel * BSTRIDE + v * 1024 + ucol * 4;
    }

    const char* projB = (const char*)proj;
    const float xc = ((float)(x0 + threadIdx.x) - 63.5f) * 2.f;
    const float yc = ((float)(y0 + threadIdx.y) - 63.5f) * 2.f;

    float* l0 = (float*)&patch[0][0] + wv * 768;
    float* l1 = (float*)&patch[1][0] + wv * 768;

    v2f acc[ZPT];
    #pragma unroll
    for (int k = 0; k < ZPT; ++k) acc[k] = (v2f){0.f, 0.f};

    // prologue: stage angle 0 into patch[0]
    {
        const int2 lo = bb_sh[0];
        const uint32_t aoff = __builtin_amdgcn_readfirstlane(
            ((uint32_t)lo.y << 10) + ((uint32_t)lo.x << 2));
        stage12(projB + aoff, l0, goffB);
    }
    __syncthreads();   // implicit vmcnt(0) drain -> patch[0] ready

    for (int a = 0; a < NA; a += 2) {
        {   // stage a+1 -> patch[1] while computing a from patch[0]
            const int2 lo = bb_sh[a + 1];
            const uint32_t aoff = __builtin_amdgcn_readfirstlane(
                (uint32_t)(a + 1) * 262144u +
                ((uint32_t)lo.y << 10) + ((uint32_t)lo.x << 2));
            stage12(projB + aoff, l1, goffB);
        }
        {
            const float2 cs = cs_sh[a];
            const int2   lo = bb_sh[a];
            compute_angle(patch[0], cs.x, cs.y, xc, yc, zf0, lo.x, lo.y, acc);
        }
        __syncthreads();
        if (a + 2 < NA) {   // stage a+2 -> patch[0] while computing a+1
            const int2 lo = bb_sh[a + 2];
            const uint32_t aoff = __builtin_amdgcn_readfirstlane(
                (uint32_t)(a + 2) * 262144u +
                ((uint32_t)lo.y << 10) + ((uint32_t)lo.x << 2));
            stage12(projB + aoff, l0, goffB);
        }
        {
            const float2 cs = cs_sh[a + 1];
            const int2   lo = bb_sh[a + 1];
            compute_angle(patch[1], cs.x, cs.y, xc, yc, zf0, lo.x, lo.y, acc);
        }
        __syncthreads();
    }

    float* o0 = out + (((size_t)zb) * 128 + (y0 + threadIdx.y)) * 128
                    + (x0 + threadIdx.x);
    float* o1 = o0 + (size_t)128 * 128 * 128;   // batch 1 volume
    #pragma unroll
    for (int k = 0; k < ZPT; ++k) {
        o0[(size_t)k * (128 * 128)] = acc[k].x;
        o1[(size_t)k * (128 * 128)] = acc[k].y;
    }
}

extern "C" void kernel_launch(void* const* d_in, const int* in_sizes, int n_in,
                              void* d_out, int out_size, void* d_ws, size_t ws_size,
                              hipStream_t stream) {
    const float* proj = (const float*)d_in[0];
    float* out = (float*)d_out;
    dim3 grid(128 / ZPT, 64, 1);   // (z-groups, xy-tiles) = 1024 blocks, batch fused
    dim3 block(16, 16, 1);
    hipLaunchKernelGGL(bp_kernel, grid, block, 0, stream, proj, out);
}